// Round 8
// baseline (374.647 us; speedup 1.0000x reference)
//
#include <hip/hip_runtime.h>
#include <stdint.h>

#define BATCH 16384
#define IN_F 2048
#define OUT_F 2048

typedef unsigned short u16;
typedef __attribute__((ext_vector_type(8))) short bf16x8;
typedef __attribute__((ext_vector_type(4))) float f32x4;

__device__ __forceinline__ u16 f2bf(float f) {
  union { float f; uint32_t u; } v; v.f = f;
  uint32_t u = v.u;
  u += 0x7FFFu + ((u >> 16) & 1u);   // round-to-nearest-even
  return (u16)(u >> 16);
}

// ---- prologue: fused fp32 -> bf16 conversion (x and w*mask in one launch) ----

__global__ void cvt_fused(const float4* __restrict__ x, const float4* __restrict__ w,
                          const float4* __restrict__ m, u16* __restrict__ xb,
                          u16* __restrict__ wb) {
  const int NX = BATCH * IN_F / 4;
  int i = blockIdx.x * 256 + threadIdx.x;
  if (i < NX) {
    float4 v = x[i];
    uint2 p;
    p.x = (uint32_t)f2bf(v.x) | ((uint32_t)f2bf(v.y) << 16);
    p.y = (uint32_t)f2bf(v.z) | ((uint32_t)f2bf(v.w) << 16);
    ((uint2*)xb)[i] = p;
  } else {
    int j = i - NX;
    float4 wv = w[j];
    float4 mv = m[j];
    uint2 p;
    p.x = (uint32_t)f2bf(wv.x * mv.x) | ((uint32_t)f2bf(wv.y * mv.y) << 16);
    p.y = (uint32_t)f2bf(wv.z * mv.z) | ((uint32_t)f2bf(wv.w * mv.w) << 16);
    ((uint2*)wb)[j] = p;
  }
}

// ---- async global->LDS 16B copy ----

__device__ __forceinline__ void async_cp16(const void* g, void* l) {
  __builtin_amdgcn_global_load_lds(
      (const __attribute__((address_space(1))) void*)g,
      (__attribute__((address_space(3))) void*)l,
      16, 0, 0);
}

// ---- bf16 MFMA GEMM: C[M][N] = A[M][K] * B[N][K]^T + bias ----
// RERUN of r7 (infra failure, no kernel signal): m201-style per-phase
// schedule on the r2/r6-verified memory system. Memory system UNCHANGED
// (proven 0 conflicts, correct ledger): 256x256 tile, BK=32, 512 threads =
// 8 waves (2M x 4N), wave tile 128x64, 16x16x32 MFMA, 4-slot LDS ring
// (128 KiB), depth-3 prefetch, literal slots, chunk swizzle c ^= (r>>1)&3
// with pre-swizzled global source.
// Schedule: per K-tile, two phases (m196/m198/m201 discipline):
//   P1: {read af0(4)+bf(4); stageA(t+3); barrier; lgkmcnt(0)+sched_barrier;
//        setprio(1); 16 MFMA (mh0); setprio(0); barrier}
//   P2: {read af1(4); stageB(t+3); vmcnt(4); barrier; lgkmcnt(0)+sched_b;
//        setprio(1); 16 MFMA (mh1); setprio(0); barrier}
// vmcnt(4) once per tile (counted, never 0 in loop). Ledger: before tile t,
// outstanding = {A,B}(t+2) [4 ops]. P1/P2 issue {A,B}(t+3) [4 ops] -> 8;
// the wait leaves 4 -> retires {A,B}(t+2): tile t+1 resident one tile
// early. Prologue: 12 ops, vmcnt(4) retires tiles 0,1.
// WAR safety (>=1 barrier between last read and overwrite):
//  - stageA at P1(t) overwrites A(t-1) [slot (t+3)&3=(t-1)&3]; last A(t-1)
//    reads = af1 at P2(t-1), complete at P2(t-1) mid-barrier lgkm0, and
//    P2(t-1)'s close barrier precedes P1(t). OK.
//  - stageB at P2(t) overwrites B(t-1); last B(t-1) reads = bf at P1(t-1);
//    multiple barriers since. OK.
// rule 18: every inline-asm lgkmcnt(0) is followed by sched_barrier(0) so
// hipcc cannot hoist register-only MFMAs above the wait.

#define BK 32
#define NT (IN_F / BK)   // 64 K-tiles

__global__ __launch_bounds__(512, 2) void gemm_bf16(const u16* __restrict__ A,
                                                    const u16* __restrict__ B,
                                                    const float* __restrict__ bias,
                                                    float* __restrict__ C) {
  __shared__ __align__(128) char smem[4 * 32768];
  const int K = IN_F, N = OUT_F;
  const int tid = threadIdx.x;
  const int lane = tid & 63, wave = tid >> 6;
  const int wm = wave >> 2;          // 0..1  (M half)
  const int wn = wave & 3;           // 0..3  (N quarter)
  const long bn = (long)blockIdx.x * 256;   // x = bn-stripe: per-XCD B panel L2 residency
  const long bm = (long)blockIdx.y * 256;

  // ---- staging: thread tid stages row sr=tid>>2, phys chunk sc=tid&3
  const int sr = tid >> 2, sc = tid & 3;
  const int scs = sc ^ ((sr >> 1) & 3);
  const u16* gA = A + (bm + sr) * K + scs * 8;
  const u16* gB = B + (bn + sr) * K + scs * 8;
  const long hiK = 128L * K;                 // (r+128)>>1 == r>>1 (mod 4): same swizzle
  const int ldst = tid * 16;

  auto stageA = [&](int slot, int kt) {
    char* sb = smem + slot * 32768;
    const long ko = (long)kt * BK;
    async_cp16(gA + ko, sb + ldst);
    async_cp16(gA + hiK + ko, sb + 8192 + ldst);
  };
  auto stageB = [&](int slot, int kt) {
    char* sb = smem + slot * 32768 + 16384;
    const long ko = (long)kt * BK;
    async_cp16(gB + ko, sb + ldst);
    async_cp16(gB + hiK + ko, sb + 8192 + ldst);
  };

  // ---- fragment read offset (row-swizzle depends only on lane&15)
  const int rl = lane & 15;
  const int q = lane >> 4;
  const int fb = rl * 64 + ((q ^ ((rl >> 1) & 3)) * 16);
  const int aoff = wm * 8192;
  const int boff = 16384 + wn * 4096;

#define LDA(SLOT, I, HALF) \
  (*(const bf16x8*)(smem + (SLOT) * 32768 + aoff + (HALF) * 4096 + (I) * 1024 + fb))
#define LDB(SLOT, J) \
  (*(const bf16x8*)(smem + (SLOT) * 32768 + boff + (J) * 1024 + fb))

  f32x4 acc[8][4];
#pragma unroll
  for (int i = 0; i < 8; i++)
#pragma unroll
    for (int j = 0; j < 4; j++)
#pragma unroll
      for (int r = 0; r < 4; r++) acc[i][j][r] = 0.0f;

  // ---- prologue: stage tiles 0,1,2; retire tiles 0 and 1 (vmcnt 4)
  stageA(0, 0); stageB(0, 0);
  stageA(1, 1); stageB(1, 1);
  stageA(2, 2); stageB(2, 2);
  asm volatile("s_waitcnt vmcnt(4)" ::: "memory");
  __builtin_amdgcn_s_barrier();

  // TILE: two phases per K-tile, m201 discipline. SLOT is a literal.
#define TILE(T, SLOT)                                                            \
  do {                                                                           \
    const int t_ = (T);                                                          \
    const int kt3_ = (t_ + 3 < NT) ? (t_ + 3) : (NT - 1);                        \
    /* ---- P1: reads for mh0 + B; stage A(t+3) ---- */                          \
    bf16x8 af0_[4], bf_[4], af1_[4];                                             \
    _Pragma("unroll")                                                            \
    for (int i = 0; i < 4; i++) af0_[i] = LDA(SLOT, i, 0);                       \
    _Pragma("unroll")                                                            \
    for (int j = 0; j < 4; j++) bf_[j] = LDB(SLOT, j);                           \
    stageA(((SLOT) + 3) & 3, kt3_);                                              \
    __builtin_amdgcn_s_barrier();                                                \
    asm volatile("s_waitcnt lgkmcnt(0)" ::: "memory");                           \
    __builtin_amdgcn_sched_barrier(0);                                           \
    __builtin_amdgcn_s_setprio(1);                                               \
    _Pragma("unroll")                                                            \
    for (int i = 0; i < 4; i++)                                                  \
      _Pragma("unroll")                                                          \
      for (int j = 0; j < 4; j++)                                                \
        acc[i][j] = __builtin_amdgcn_mfma_f32_16x16x32_bf16(                     \
            af0_[i], bf_[j], acc[i][j], 0, 0, 0);                                \
    __builtin_amdgcn_s_setprio(0);                                               \
    __builtin_amdgcn_s_barrier();                                                \
    /* ---- P2: reads for mh1; stage B(t+3); counted vmcnt ---- */               \
    _Pragma("unroll")                                                            \
    for (int i = 0; i < 4; i++) af1_[i] = LDA(SLOT, i, 1);                       \
    stageB(((SLOT) + 3) & 3, kt3_);                                              \
    asm volatile("s_waitcnt vmcnt(4)" ::: "memory");                             \
    __builtin_amdgcn_s_barrier();                                                \
    asm volatile("s_waitcnt lgkmcnt(0)" ::: "memory");                           \
    __builtin_amdgcn_sched_barrier(0);                                           \
    __builtin_amdgcn_s_setprio(1);                                               \
    _Pragma("unroll")                                                            \
    for (int i = 0; i < 4; i++)                                                  \
      _Pragma("unroll")                                                          \
      for (int j = 0; j < 4; j++)                                                \
        acc[4 + i][j] = __builtin_amdgcn_mfma_f32_16x16x32_bf16(                 \
            af1_[i], bf_[j], acc[4 + i][j], 0, 0, 0);                            \
    __builtin_amdgcn_s_setprio(0);                                               \
    __builtin_amdgcn_s_barrier();                                                \
  } while (0)

  for (int t = 0; t < NT; t += 4) {
    TILE(t + 0, 0);
    TILE(t + 1, 1);
    TILE(t + 2, 2);
    TILE(t + 3, 3);
  }
#undef TILE
#undef LDA
#undef LDB

  // drain leftover clamped-tail stages before LDS goes away
  asm volatile("s_waitcnt vmcnt(0)" ::: "memory");

  // ---- epilogue: C/D layout col=lane&15, row=(lane>>4)*4+r  [m89-verified]
  const int cn = lane & 15;
  const int crow = (lane >> 4) * 4;
#pragma unroll
  for (int j = 0; j < 4; j++) {
    const long n = bn + wn * 64 + j * 16 + cn;
    const float bv = bias[n];
#pragma unroll
    for (int i = 0; i < 8; i++) {
      const long m0 = bm + wm * 128 + i * 16 + crow;
      float* cp = C + m0 * N + n;
#pragma unroll
      for (int r = 0; r < 4; r++)
        cp[(long)r * N] = acc[i][j][r] + bv;
    }
  }
}

// ---- fallback (only if d_ws is too small): exact fp32, slow but correct ----

__global__ void naive_kernel(const float* __restrict__ x, const float* __restrict__ w,
                             const float* __restrict__ bias, const float* __restrict__ m,
                             float* __restrict__ out) {
  size_t idx = (size_t)blockIdx.x * 256 + threadIdx.x;
  int o = (int)(idx % OUT_F);
  size_t b = idx / OUT_F;
  float s = bias[o];
  const float* xr = x + b * IN_F;
  const float* wr = w + (size_t)o * IN_F;
  const float* mr = m + (size_t)o * IN_F;
  for (int k = 0; k < IN_F; k++) s += xr[k] * wr[k] * mr[k];
  out[idx] = s;
}

extern "C" void kernel_launch(void* const* d_in, const int* in_sizes, int n_in,
                              void* d_out, int out_size, void* d_ws, size_t ws_size,
                              hipStream_t stream) {
  const float* x = (const float*)d_in[0];
  const float* w = (const float*)d_in[1];
  const float* bias = (const float*)d_in[2];
  const float* mask = (const float*)d_in[3];
  float* out = (float*)d_out;

  const size_t xb_elems = (size_t)BATCH * IN_F;       // 33.5M bf16 = 64 MB
  const size_t wm_elems = (size_t)OUT_F * IN_F;       // 4.2M bf16 = 8 MB
  const size_t need = (xb_elems + wm_elems) * sizeof(u16);

  if (ws_size >= need) {
    u16* xb = (u16*)d_ws;
    u16* wm = xb + xb_elems;
    const uint32_t nblk = (uint32_t)((xb_elems + wm_elems) / 4 / 256);
    cvt_fused<<<nblk, 256, 0, stream>>>((const float4*)x, (const float4*)w,
                                        (const float4*)mask, xb, wm);
    gemm_bf16<<<dim3(OUT_F / 256, BATCH / 256), 512, 0, stream>>>(xb, wm, bias, out);
  } else {
    naive_kernel<<<(uint32_t)(((size_t)BATCH * OUT_F) / 256), 256, 0, stream>>>(x, w, bias, mask, out);
  }
}

// Round 9
// 357.492 us; speedup vs baseline: 1.0480x; 1.0480x over previous
//
#include <hip/hip_runtime.h>
#include <stdint.h>

#define BATCH 16384
#define IN_F 2048
#define OUT_F 2048

typedef unsigned short u16;
typedef __attribute__((ext_vector_type(8))) short bf16x8;
typedef __attribute__((ext_vector_type(4))) float f32x4;

__device__ __forceinline__ u16 f2bf(float f) {
  union { float f; uint32_t u; } v; v.f = f;
  uint32_t u = v.u;
  u += 0x7FFFu + ((u >> 16) & 1u);   // round-to-nearest-even
  return (u16)(u >> 16);
}

// ---- prologue: fused fp32 -> bf16 conversion (x and w*mask in one launch) ----

__global__ void cvt_fused(const float4* __restrict__ x, const float4* __restrict__ w,
                          const float4* __restrict__ m, u16* __restrict__ xb,
                          u16* __restrict__ wb) {
  const int NX = BATCH * IN_F / 4;
  int i = blockIdx.x * 256 + threadIdx.x;
  if (i < NX) {
    float4 v = x[i];
    uint2 p;
    p.x = (uint32_t)f2bf(v.x) | ((uint32_t)f2bf(v.y) << 16);
    p.y = (uint32_t)f2bf(v.z) | ((uint32_t)f2bf(v.w) << 16);
    ((uint2*)xb)[i] = p;
  } else {
    int j = i - NX;
    float4 wv = w[j];
    float4 mv = m[j];
    uint2 p;
    p.x = (uint32_t)f2bf(wv.x * mv.x) | ((uint32_t)f2bf(wv.y * mv.y) << 16);
    p.y = (uint32_t)f2bf(wv.z * mv.z) | ((uint32_t)f2bf(wv.w * mv.w) << 16);
    ((uint2*)wb)[j] = p;
  }
}

// ---- async global->LDS 16B copy ----

__device__ __forceinline__ void async_cp16(const void* g, void* l) {
  __builtin_amdgcn_global_load_lds(
      (const __attribute__((address_space(1))) void*)g,
      (__attribute__((address_space(3))) void*)l,
      16, 0, 0);
}

// ---- bf16 MFMA GEMM: C[M][N] = A[M][K] * B[N][K]^T + bias ----
// THIS ROUND: BK 32 -> 64 to amortize the measured ~1270 cyc/iter sync
// overhead over 2x the FLOPs (r6 accounting: period 2515, MFMA busy 1076,
// sync ~1270 paid once per K-tile; r7/r8 proved more barriers = worse).
// r8 (phase-barrier port) REVERTED per pre-commit.
// Geometry: 256x256 tile, 512 thr = 8 waves (2M x 4N), wave tile 128x64,
// 16x16x32 MFMA (r2-verified reads; 32-row frags banned per r3/r4).
// LDS: 2-slot double-buffer of 64 KB K-tiles (A 32K + B 32K), 128 KiB.
// Per iter (32 iters): stage(t+1) [8 ops] at TOP, 24 ds_read_b128/wave
// interleaved under 4x16 MFMA clusters, ONE vmcnt(0)+barrier at END.
// Depth-1 drain is cheap here: the waited loads were issued a full iter
// (~2400 cyc) earlier (m97's drain disease was FRESH loads).
// WAR safety: stage(S^1) at iter t overwrites tile t-1, whose ds_reads all
// completed before iter t-1's closing barrier (lgkm-drained before MFMA use).
// Swizzle (128B rows = 8 chunks of 16B): phys chunk c of row r holds
// logical chunk c ^ (r&7); staging pre-swizzles the global source column
// (global_load_lds dest stays linear), reads apply the same XOR.
// Uniformity proof: frag read lanes (rl 0-15, q 0-3) hit bank-quad
// (kh*4+q)^(rl&7): each of 8 quads gets exactly 8 lanes = structural
// minimum (same property as r2's measured-0 layout). Row terms (16,64,128
// multiples) drop out of r&7; op stride 64 preserves staging swizzle.
// Operand k-map: lane q holds k = q*8..q*8+7 -> k-half kh at byte
// kh*64 + q*16 within the 128B row.

#define BKK 64
#define NT2 (IN_F / BKK)   // 32 K-tiles

__global__ __launch_bounds__(512, 2) void gemm_bf16(const u16* __restrict__ A,
                                                    const u16* __restrict__ B,
                                                    const float* __restrict__ bias,
                                                    float* __restrict__ C) {
  __shared__ __align__(128) char smem[2 * 65536];
  const int K = IN_F, N = OUT_F;
  const int tid = threadIdx.x;
  const int lane = tid & 63, wave = tid >> 6;
  const int wm = wave >> 2;          // 0..1  (M half)
  const int wn = wave & 3;           // 0..3  (N quarter)
  const long bn = (long)blockIdx.x * 256;   // x = bn-stripe: id%8 = XCD -> B panel L2-resident
  const long bm = (long)blockIdx.y * 256;

  // ---- staging: thread tid stages row sr=tid>>3 (+64*op), phys chunk sc=tid&7
  const int sr = tid >> 3, sc = tid & 7;
  const int scs = sc ^ (sr & 7);             // logical (global) chunk for this slot
  const u16* gA = A + (bm + sr) * K + scs * 8;
  const u16* gB = B + (bn + sr) * K + scs * 8;
  const int ldst = tid * 16;                 // linear dest within an 8 KB op region

  auto stageA = [&](int slot, int kt) {
    char* sb = smem + slot * 65536;
    const long ko = (long)kt * BKK;
#pragma unroll
    for (int op = 0; op < 4; op++)
      async_cp16(gA + (long)op * 64 * K + ko, sb + op * 8192 + ldst);
  };
  auto stageB = [&](int slot, int kt) {
    char* sb = smem + slot * 65536 + 32768;
    const long ko = (long)kt * BKK;
#pragma unroll
    for (int op = 0; op < 4; op++)
      async_cp16(gB + (long)op * 64 * K + ko, sb + op * 8192 + ldst);
  };

  // ---- fragment read geometry: row*128 + ((kh*4+q) ^ (row&7))*16, row&7 = rl&7
  const int rl = lane & 15;
  const int q = lane >> 4;
  const int x0 = ((0 + q) ^ (rl & 7)) * 16;  // kh=0
  const int x1 = ((4 + q) ^ (rl & 7)) * 16;  // kh=1
  const int arow = wm * 128 + rl;            // + HALF*64 + I*16
  const int brow = wn * 64 + rl;             // + J*16

#define LDA(SLOT, I, HALF, KH)                                              \
  (*(const bf16x8*)(smem + (SLOT) * 65536 +                                 \
                    (arow + (HALF) * 64 + (I) * 16) * 128 + ((KH) ? x1 : x0)))
#define LDB(SLOT, J, KH)                                                    \
  (*(const bf16x8*)(smem + (SLOT) * 65536 + 32768 +                         \
                    (brow + (J) * 16) * 128 + ((KH) ? x1 : x0)))

  f32x4 acc[8][4];
#pragma unroll
  for (int i = 0; i < 8; i++)
#pragma unroll
    for (int j = 0; j < 4; j++)
#pragma unroll
      for (int r = 0; r < 4; r++) acc[i][j][r] = 0.0f;

  // ---- prologue: stage tile 0 into slot 0; drain; barrier
  stageA(0, 0);
  stageB(0, 0);
  asm volatile("s_waitcnt vmcnt(0)" ::: "memory");
  __builtin_amdgcn_s_barrier();

  // BODY: one 64-deep K-step. SLOT literal. Reads are placed just before
  // their dependent cluster; compiler interleaves them under the previous
  // cluster's MFMAs with fine-grained lgkmcnt (m97-verified behavior).
#define CLUSTER(ACCBASE, AF, BF)                                                 \
  do {                                                                           \
    __builtin_amdgcn_s_setprio(1);                                               \
    _Pragma("unroll")                                                            \
    for (int i = 0; i < 4; i++)                                                  \
      _Pragma("unroll")                                                          \
      for (int j = 0; j < 4; j++)                                                \
        acc[(ACCBASE) + i][j] = __builtin_amdgcn_mfma_f32_16x16x32_bf16(         \
            AF[i], BF[j], acc[(ACCBASE) + i][j], 0, 0, 0);                       \
    __builtin_amdgcn_s_setprio(0);                                               \
  } while (0)

#define BODY(T, SLOT)                                                            \
  do {                                                                           \
    const int t_ = (T);                                                          \
    const int ktn_ = (t_ + 1 < NT2) ? (t_ + 1) : (NT2 - 1);                      \
    stageA((SLOT) ^ 1, ktn_);                                                    \
    stageB((SLOT) ^ 1, ktn_);                                                    \
    bf16x8 a0_[4], a1_[4], b0_[4], a2_[4], a3_[4], b1_[4];                       \
    _Pragma("unroll")                                                            \
    for (int i = 0; i < 4; i++) a0_[i] = LDA(SLOT, i, 0, 0);                     \
    _Pragma("unroll")                                                            \
    for (int j = 0; j < 4; j++) b0_[j] = LDB(SLOT, j, 0);                        \
    CLUSTER(0, a0_, b0_);                                                        \
    _Pragma("unroll")                                                            \
    for (int i = 0; i < 4; i++) a1_[i] = LDA(SLOT, i, 1, 0);                     \
    CLUSTER(4, a1_, b0_);                                                        \
    _Pragma("unroll")                                                            \
    for (int i = 0; i < 4; i++) a2_[i] = LDA(SLOT, i, 0, 1);                     \
    _Pragma("unroll")                                                            \
    for (int j = 0; j < 4; j++) b1_[j] = LDB(SLOT, j, 1);                        \
    CLUSTER(0, a2_, b1_);                                                        \
    _Pragma("unroll")                                                            \
    for (int i = 0; i < 4; i++) a3_[i] = LDA(SLOT, i, 1, 1);                     \
    CLUSTER(4, a3_, b1_);                                                        \
    asm volatile("s_waitcnt vmcnt(0)" ::: "memory");                             \
    __builtin_amdgcn_s_barrier();                                                \
  } while (0)

  for (int t = 0; t < NT2; t += 2) {
    BODY(t + 0, 0);
    BODY(t + 1, 1);
  }
#undef BODY
#undef CLUSTER
#undef LDA
#undef LDB

  // ---- epilogue: C/D layout col=lane&15, row=(lane>>4)*4+r  [m89-verified]
  const int cn = lane & 15;
  const int crow = (lane >> 4) * 4;
#pragma unroll
  for (int j = 0; j < 4; j++) {
    const long n = bn + wn * 64 + j * 16 + cn;
    const float bv = bias[n];
#pragma unroll
    for (int i = 0; i < 8; i++) {
      const long m0 = bm + wm * 128 + i * 16 + crow;
      float* cp = C + m0 * N + n;
#pragma unroll
      for (int r = 0; r < 4; r++)
        cp[(long)r * N] = acc[i][j][r] + bv;
    }
  }
}

// ---- fallback (only if d_ws is too small): exact fp32, slow but correct ----

__global__ void naive_kernel(const float* __restrict__ x, const float* __restrict__ w,
                             const float* __restrict__ bias, const float* __restrict__ m,
                             float* __restrict__ out) {
  size_t idx = (size_t)blockIdx.x * 256 + threadIdx.x;
  int o = (int)(idx % OUT_F);
  size_t b = idx / OUT_F;
  float s = bias[o];
  const float* xr = x + b * IN_F;
  const float* wr = w + (size_t)o * IN_F;
  const float* mr = m + (size_t)o * IN_F;
  for (int k = 0; k < IN_F; k++) s += xr[k] * wr[k] * mr[k];
  out[idx] = s;
}

extern "C" void kernel_launch(void* const* d_in, const int* in_sizes, int n_in,
                              void* d_out, int out_size, void* d_ws, size_t ws_size,
                              hipStream_t stream) {
  const float* x = (const float*)d_in[0];
  const float* w = (const float*)d_in[1];
  const float* bias = (const float*)d_in[2];
  const float* mask = (const float*)d_in[3];
  float* out = (float*)d_out;

  const size_t xb_elems = (size_t)BATCH * IN_F;       // 33.5M bf16 = 64 MB
  const size_t wm_elems = (size_t)OUT_F * IN_F;       // 4.2M bf16 = 8 MB
  const size_t need = (xb_elems + wm_elems) * sizeof(u16);

  if (ws_size >= need) {
    u16* xb = (u16*)d_ws;
    u16* wm = xb + xb_elems;
    const uint32_t nblk = (uint32_t)((xb_elems + wm_elems) / 4 / 256);
    cvt_fused<<<nblk, 256, 0, stream>>>((const float4*)x, (const float4*)w,
                                        (const float4*)mask, xb, wm);
    gemm_bf16<<<dim3(OUT_F / 256, BATCH / 256), 512, 0, stream>>>(xb, wm, bias, out);
  } else {
    naive_kernel<<<(uint32_t)(((size_t)BATCH * OUT_F) / 256), 256, 0, stream>>>(x, w, bias, mask, out);
  }
}

// Round 11
// 354.129 us; speedup vs baseline: 1.0579x; 1.0095x over previous
//
#include <hip/hip_runtime.h>
#include <stdint.h>

#define BATCH 16384
#define IN_F 2048
#define OUT_F 2048

typedef unsigned short u16;
typedef __attribute__((ext_vector_type(8))) short bf16x8;
typedef __attribute__((ext_vector_type(4))) float f32x4;
typedef __attribute__((ext_vector_type(4))) float nf4;   // native vec4 for nontemporal builtins

__device__ __forceinline__ u16 f2bf(float f) {
  union { float f; uint32_t u; } v; v.f = f;
  uint32_t u = v.u;
  u += 0x7FFFu + ((u >> 16) & 1u);   // round-to-nearest-even
  return (u16)(u >> 16);
}

// ---- prologue: fused fp32 -> bf16 conversion (x and w*mask in one launch) ----
// r10: inputs are read-once -> NON-TEMPORAL loads (don't evict L3 lines the
// gemm is about to need for xb/wm). xb/wm writes stay cached (re-read soon).
// Loads go through clang ext_vector_type (HIP_vector_type structs are
// rejected by __builtin_nontemporal_load).

__global__ void cvt_fused(const float* __restrict__ x, const float* __restrict__ w,
                          const float* __restrict__ m, u16* __restrict__ xb,
                          u16* __restrict__ wb) {
  const int NX = BATCH * IN_F / 4;
  int i = blockIdx.x * 256 + threadIdx.x;
  if (i < NX) {
    nf4 v = __builtin_nontemporal_load((const nf4*)x + i);
    uint2 p;
    p.x = (uint32_t)f2bf(v.x) | ((uint32_t)f2bf(v.y) << 16);
    p.y = (uint32_t)f2bf(v.z) | ((uint32_t)f2bf(v.w) << 16);
    ((uint2*)xb)[i] = p;
  } else {
    int j = i - NX;
    nf4 wv = __builtin_nontemporal_load((const nf4*)w + j);
    nf4 mv = __builtin_nontemporal_load((const nf4*)m + j);
    uint2 p;
    p.x = (uint32_t)f2bf(wv.x * mv.x) | ((uint32_t)f2bf(wv.y * mv.y) << 16);
    p.y = (uint32_t)f2bf(wv.z * mv.z) | ((uint32_t)f2bf(wv.w * mv.w) << 16);
    ((uint2*)wb)[j] = p;
  }
}

// ---- async global->LDS 16B copy ----

__device__ __forceinline__ void async_cp16(const void* g, void* l) {
  __builtin_amdgcn_global_load_lds(
      (const __attribute__((address_space(1))) void*)g,
      (__attribute__((address_space(3))) void*)l,
      16, 0, 0);
}

// ---- bf16 MFMA GEMM: C[M][N] = A[M][K] * B[N][K]^T + bias ----
// r10 = r6 (best measured: 134.0 us, MfmaUtil 42.8, 0 conflicts) with ONE
// change: NON-TEMPORAL C stores. Theory: r2..r9 schedule variants are all
// pinned at 134-148 us -> bottleneck is staging SUPPLY, not sync. FETCH=270MB
// vs 72MB compulsory shows A re-fetches (8 XCDs re-read each A panel) miss
// L3 because 128 MB of streaming C stores thrash Infinity Cache. nt-stores
// keep C out of L2/L3 so xb stays L3-resident and A re-fetches hit L3.
// Structure (r6, unchanged): 256x256 tile, BK=32, 512 thr = 8 waves
// (2M x 4N), wave tile 128x64, 16x16x32 MFMA, 4-slot LDS ring (128 KiB),
// depth-3 prefetch, counted vmcnt(4) once per iter, one barrier per iter,
// literal ring slots, cross-iter register prefetch (tile t+1 frags read
// during iter t's MFMA clusters).
// Safety invariant (r2-verified): at end of iter t (after vmcnt(4)), tiles
// <= t+2 resident, tile t+3 in flight. Prefetch reads of slot (t+1)&3
// during iter t safe; stage target slot (t+3)&3 = (t-1)&3 last read in
// iter t-1 (lgkm-drained before its MFMA use, barrier since).
// Swizzle (r2-verified 0 conflicts): physical 16B chunk c of row r holds
// logical chunk c ^ ((r>>1)&3); staging pre-swizzles the global source
// column (global_load_lds dest must stay linear), reads apply the same XOR.

#define BK 32
#define NT (IN_F / BK)   // 64 K-tiles

__global__ __launch_bounds__(512, 2) void gemm_bf16(const u16* __restrict__ A,
                                                    const u16* __restrict__ B,
                                                    const float* __restrict__ bias,
                                                    float* __restrict__ C) {
  __shared__ __align__(128) char smem[4 * 32768];
  const int K = IN_F, N = OUT_F;
  const int tid = threadIdx.x;
  const int lane = tid & 63, wave = tid >> 6;
  const int wm = wave >> 2;          // 0..1  (M half)
  const int wn = wave & 3;           // 0..3  (N quarter)
  const long bn = (long)blockIdx.x * 256;   // x = bn-stripe: per-XCD B panel L2 residency
  const long bm = (long)blockIdx.y * 256;

  // ---- staging: thread tid stages row sr=tid>>2, phys chunk sc=tid&3
  const int sr = tid >> 2, sc = tid & 3;
  const int scs = sc ^ ((sr >> 1) & 3);
  const u16* gA = A + (bm + sr) * K + scs * 8;
  const u16* gB = B + (bn + sr) * K + scs * 8;
  const long hiK = 128L * K;                 // (r+128)>>1 == r>>1 (mod 4): same swizzle
  const int ldst = tid * 16;

  auto stageA = [&](int slot, int kt) {
    char* sb = smem + slot * 32768;
    const long ko = (long)kt * BK;
    async_cp16(gA + ko, sb + ldst);
    async_cp16(gA + hiK + ko, sb + 8192 + ldst);
  };
  auto stageB = [&](int slot, int kt) {
    char* sb = smem + slot * 32768 + 16384;
    const long ko = (long)kt * BK;
    async_cp16(gB + ko, sb + ldst);
    async_cp16(gB + hiK + ko, sb + 8192 + ldst);
  };

  // ---- fragment read offset (row-swizzle depends only on lane&15)
  const int rl = lane & 15;
  const int q = lane >> 4;
  const int fb = rl * 64 + ((q ^ ((rl >> 1) & 3)) * 16);
  const int aoff = wm * 8192;
  const int boff = 16384 + wn * 4096;

#define LDA(SLOT, I, HALF) \
  (*(const bf16x8*)(smem + (SLOT) * 32768 + aoff + (HALF) * 4096 + (I) * 1024 + fb))
#define LDB(SLOT, J) \
  (*(const bf16x8*)(smem + (SLOT) * 32768 + boff + (J) * 1024 + fb))

  f32x4 acc[8][4];
#pragma unroll
  for (int i = 0; i < 8; i++)
#pragma unroll
    for (int j = 0; j < 4; j++)
#pragma unroll
      for (int r = 0; r < 4; r++) acc[i][j][r] = 0.0f;

  // ---- prologue: stage tiles 0,1,2; retire tiles 0 and 1 (vmcnt 4)
  stageA(0, 0); stageB(0, 0);
  stageA(1, 1); stageB(1, 1);
  stageA(2, 2); stageB(2, 2);
  asm volatile("s_waitcnt vmcnt(4)" ::: "memory");
  __builtin_amdgcn_s_barrier();

  // preload tile-0 fragments (A M-half0 + B) into the A-set
  bf16x8 afA[4], bfA[4], afB[4], bfB[4];
#pragma unroll
  for (int i = 0; i < 4; i++) afA[i] = LDA(0, i, 0);
#pragma unroll
  for (int j = 0; j < 4; j++) bfA[j] = LDB(0, j);

  // BODY: stage t+3 (literal slot); read A M-half1 under cluster 1; read
  // next-iter A M-half0 + B (tile t+1, literal slot) under cluster 2;
  // counted vmcnt(4); one barrier.
#define BODY(T, SLOT, curA, curB, nxtA, nxtB)                                    \
  do {                                                                           \
    const int t_ = (T);                                                          \
    const int kt3_ = (t_ + 3 < NT) ? (t_ + 3) : (NT - 1);                        \
    stageA(((SLOT) + 3) & 3, kt3_);                                              \
    stageB(((SLOT) + 3) & 3, kt3_);                                              \
    bf16x8 af1_[4];                                                              \
    _Pragma("unroll")                                                            \
    for (int i = 0; i < 4; i++) af1_[i] = LDA(SLOT, i, 1);                       \
    __builtin_amdgcn_s_setprio(1);                                               \
    _Pragma("unroll")                                                            \
    for (int i = 0; i < 4; i++)                                                  \
      _Pragma("unroll")                                                          \
      for (int j = 0; j < 4; j++)                                                \
        acc[i][j] = __builtin_amdgcn_mfma_f32_16x16x32_bf16(                     \
            curA[i], curB[j], acc[i][j], 0, 0, 0);                               \
    __builtin_amdgcn_s_setprio(0);                                               \
    _Pragma("unroll")                                                            \
    for (int i = 0; i < 4; i++) nxtA[i] = LDA(((SLOT) + 1) & 3, i, 0);           \
    _Pragma("unroll")                                                            \
    for (int j = 0; j < 4; j++) nxtB[j] = LDB(((SLOT) + 1) & 3, j);              \
    __builtin_amdgcn_s_setprio(1);                                               \
    _Pragma("unroll")                                                            \
    for (int i = 0; i < 4; i++)                                                  \
      _Pragma("unroll")                                                          \
      for (int j = 0; j < 4; j++)                                                \
        acc[4 + i][j] = __builtin_amdgcn_mfma_f32_16x16x32_bf16(                 \
            af1_[i], curB[j], acc[4 + i][j], 0, 0, 0);                           \
    __builtin_amdgcn_s_setprio(0);                                               \
    asm volatile("s_waitcnt vmcnt(4)" ::: "memory");                             \
    __builtin_amdgcn_s_barrier();                                                \
  } while (0)

  for (int t = 0; t < NT; t += 4) {
    BODY(t + 0, 0, afA, bfA, afB, bfB);
    BODY(t + 1, 1, afB, bfB, afA, bfA);
    BODY(t + 2, 2, afA, bfA, afB, bfB);
    BODY(t + 3, 3, afB, bfB, afA, bfA);
  }
#undef BODY
#undef LDA
#undef LDB

  // drain leftover clamped-tail stages before LDS goes away
  asm volatile("s_waitcnt vmcnt(0)" ::: "memory");

  // ---- epilogue: C/D layout col=lane&15, row=(lane>>4)*4+r  [m89-verified]
  // r10: NON-TEMPORAL stores — C is write-once; keep it out of L2/L3 so the
  // xb panel stays Infinity-Cache-resident for the A re-fetch stream.
  const int cn = lane & 15;
  const int crow = (lane >> 4) * 4;
#pragma unroll
  for (int j = 0; j < 4; j++) {
    const long n = bn + wn * 64 + j * 16 + cn;
    const float bv = bias[n];
#pragma unroll
    for (int i = 0; i < 8; i++) {
      const long m0 = bm + wm * 128 + i * 16 + crow;
      float* cp = C + m0 * N + n;
#pragma unroll
      for (int r = 0; r < 4; r++)
        __builtin_nontemporal_store(acc[i][j][r] + bv, cp + (long)r * N);
    }
  }
}

// ---- fallback (only if d_ws is too small): exact fp32, slow but correct ----

__global__ void naive_kernel(const float* __restrict__ x, const float* __restrict__ w,
                             const float* __restrict__ bias, const float* __restrict__ m,
                             float* __restrict__ out) {
  size_t idx = (size_t)blockIdx.x * 256 + threadIdx.x;
  int o = (int)(idx % OUT_F);
  size_t b = idx / OUT_F;
  float s = bias[o];
  const float* xr = x + b * IN_F;
  const float* wr = w + (size_t)o * IN_F;
  const float* mr = m + (size_t)o * IN_F;
  for (int k = 0; k < IN_F; k++) s += xr[k] * wr[k] * mr[k];
  out[idx] = s;
}

extern "C" void kernel_launch(void* const* d_in, const int* in_sizes, int n_in,
                              void* d_out, int out_size, void* d_ws, size_t ws_size,
                              hipStream_t stream) {
  const float* x = (const float*)d_in[0];
  const float* w = (const float*)d_in[1];
  const float* bias = (const float*)d_in[2];
  const float* mask = (const float*)d_in[3];
  float* out = (float*)d_out;

  const size_t xb_elems = (size_t)BATCH * IN_F;       // 33.5M bf16 = 64 MB
  const size_t wm_elems = (size_t)OUT_F * IN_F;       // 4.2M bf16 = 8 MB
  const size_t need = (xb_elems + wm_elems) * sizeof(u16);

  if (ws_size >= need) {
    u16* xb = (u16*)d_ws;
    u16* wm = xb + xb_elems;
    const uint32_t nblk = (uint32_t)((xb_elems + wm_elems) / 4 / 256);
    cvt_fused<<<nblk, 256, 0, stream>>>(x, w, mask, xb, wm);
    gemm_bf16<<<dim3(OUT_F / 256, BATCH / 256), 512, 0, stream>>>(xb, wm, bias, out);
  } else {
    naive_kernel<<<(uint32_t)(((size_t)BATCH * OUT_F) / 256), 256, 0, stream>>>(x, w, bias, mask, out);
  }
}